// Round 2
// baseline (28296.808 us; speedup 1.0000x reference)
//
#include <hip/hip_runtime.h>
#include <hip/hip_bf16.h>

// Problem constants: B=8, F=48, S=64, D=512, NH=8, L=4, DFF=2048, M=64, PERIOD=30
using bf16 = __hip_bfloat16;

// ---------------- helpers ----------------
__device__ inline void storeT(float* d, float v){ *d = v; }
__device__ inline void storeT(bf16* d, float v){ *d = __float2bfloat16(v); }

// load 2 consecutive bf16 -> 2 floats (4B-aligned)
__device__ inline void bf2(const bf16* p, float& f0, float& f1){
  unsigned u = *reinterpret_cast<const unsigned*>(p);
  f0 = __uint_as_float(u << 16);
  f1 = __uint_as_float(u & 0xffff0000u);
}

// ---------------- transpose (src R x C  ->  dst C x R), cast to T ----------------
template<typename T>
__global__ void k_transpose(const float* __restrict__ src, T* __restrict__ dst, int R, int C){
  __shared__ float tile[32][33];
  int cb = blockIdx.x*32, rb = blockIdx.y*32;
  int tx = threadIdx.x, ty = threadIdx.y;   // blockDim (32,8)
  for (int i=ty; i<32; i+=8) tile[i][tx] = src[(size_t)(rb+i)*C + cb+tx];
  __syncthreads();
  for (int i=ty; i<32; i+=8) storeT(&dst[(size_t)(cb+i)*R + rb+tx], tile[tx][i]);
}

// ---------------- generic linear: C[r,o] = sum_d A[r,d]*Wt[d,o] + bias[o] ----------------
// grid: (O/128, R/8), block 256.  Thread: out-pair op=tid&63, k-quarter kp=tid>>6.
__global__ void k_linear(const float* __restrict__ A, int lda,
                         const float* __restrict__ Wt, int ldw,
                         const float* __restrict__ bias,
                         float* __restrict__ C, int ldc,
                         int O, int Din){
  __shared__ float xs[8*1024];
  __shared__ float red[4096];
  int tid = threadIdx.x;
  int r0 = blockIdx.y*8;
  for (int idx=tid; idx<8*Din; idx+=256){
    int ri = idx / Din, d = idx - ri*Din;
    xs[idx] = A[(size_t)(r0+ri)*lda + d];
  }
  __syncthreads();
  int op = tid & 63, kp = tid >> 6;
  int o = blockIdx.x*128 + op*2;
  int dq = Din >> 2;
  float a0[8] = {0,0,0,0,0,0,0,0}, a1[8] = {0,0,0,0,0,0,0,0};
  for (int d = kp*dq; d < kp*dq+dq; ++d){
    float2 w = *reinterpret_cast<const float2*>(&Wt[(size_t)d*ldw + o]);
    #pragma unroll
    for (int ri=0; ri<8; ++ri){ float x = xs[ri*Din+d]; a0[ri] += x*w.x; a1[ri] += x*w.y; }
  }
  #pragma unroll
  for (int ri=0; ri<8; ++ri){
    red[((kp*64+op)*8+ri)*2]   = a0[ri];
    red[((kp*64+op)*8+ri)*2+1] = a1[ri];
  }
  __syncthreads();
  for (int idx = tid; idx < 1024; idx += 256){
    int ri = idx >> 7, oc = idx & 127;
    int opp = oc >> 1, c = oc & 1;
    float v = red[((0*64+opp)*8+ri)*2 + c] + red[((1*64+opp)*8+ri)*2 + c]
            + red[((2*64+opp)*8+ri)*2 + c] + red[((3*64+opp)*8+ri)*2 + c];
    int oo = blockIdx.x*128 + oc;
    if (bias) v += bias[oo];
    C[(size_t)(r0+ri)*ldc + oo] = v;
  }
}

// ---------------- PE table: pe[t,d], t<48, d<512 ----------------
__global__ void k_pe(float* __restrict__ pe){
  int idx = blockIdx.x*256 + threadIdx.x;  // 48*512
  int t = idx >> 9, d = idx & 511;
  int p = t % 30;
  int i2 = d & ~1;
  float div = __expf(-(float)i2 * (9.210340371976184f/512.f));  // ln(10000)/512
  float ang = (float)p * div;
  pe[idx] = (d & 1) ? cosf(ang) : sinf(ang);
}

// ---------------- sel attention (nh=1, no mask, 64 keys, dh=512) ----------------
__global__ void k_sel_attn(const float* __restrict__ qh, const float* __restrict__ kh,
                           const float* __restrict__ vh, float* __restrict__ o){
  int bf = blockIdx.x;           // b*48+f
  int b  = bf / 48;
  int tid = threadIdx.x;
  __shared__ float qs[512];
  __shared__ float ps[64];
  qs[tid] = qh[(size_t)bf*512 + tid];
  qs[tid+256] = qh[(size_t)bf*512 + tid + 256];
  __syncthreads();
  if (tid < 64){
    const float* kr = kh + (size_t)(b*64+tid)*512;
    float a = 0.f;
    for (int d=0; d<512; ++d) a += qs[d]*kr[d];
    ps[tid] = a * 0.04419417382415922f;   // 1/sqrt(512)
  }
  __syncthreads();
  if (tid == 0){
    float m = -1e30f;
    for (int j=0;j<64;++j) m = fmaxf(m, ps[j]);
    float s = 0.f;
    for (int j=0;j<64;++j){ float e = __expf(ps[j]-m); ps[j]=e; s+=e; }
    float iv = 1.f/s;
    for (int j=0;j<64;++j) ps[j] *= iv;
  }
  __syncthreads();
  float a0=0.f, a1=0.f;
  for (int j=0;j<64;++j){
    const float* vr = vh + (size_t)(b*64+j)*512;
    float pj = ps[j];
    a0 += pj*vr[tid]; a1 += pj*vr[tid+256];
  }
  o[(size_t)bf*512+tid] = a0;
  o[(size_t)bf*512+tid+256] = a1;
}

// ---------------- tiny glue kernels ----------------
__global__ void k_cat_tail(const float* __restrict__ sel, float* __restrict__ cat){
  int idx = blockIdx.x*256 + threadIdx.x;  // 8*512
  int b = idx >> 9, d = idx & 511;
  cat[b*1024 + 512 + d] = sel[(size_t)(b*48)*512 + d];
}
__global__ void k_add_style(const float* __restrict__ embt, const float* __restrict__ style,
                            float* __restrict__ emb){
  int idx = blockIdx.x*256 + threadIdx.x;  // 8*512
  emb[idx] = embt[idx] + style[idx];
}

// ---------------- persistent decode kernel (plain launch; 128 blocks <= 256 CUs
// guarantees co-residency at 1 block/CU, so the spin barrier is safe) ----------------
struct DP {
  unsigned* bar;
  float *emb_cur, *qbuf, *z1, *z3, *hbuf, *u2buf, *xpost, *newb;
  float *Kc, *Vc;
  const float *xa_c, *pe;
  const bf16 *WtQKV, *WtO, *WtF1, *WtF2;
  const float *Wt_mmr, *Wt_mm, *Wt_se;
  const float *sa_in_b, *sa_out_b, *ff1_b, *ff2_b, *mmr_b, *mm_b, *se_b, *ln_g, *ln_b, *style, *sel;
  float *dec_out;
};

__launch_bounds__(256)
__global__ void k_decode(DP p){
  const int tid = threadIdx.x;
  const int b  = blockIdx.x >> 4;   // 8 batches x 16 WGs
  const int wg = blockIdx.x & 15;
  unsigned* bar = p.bar + b*64;
  unsigned nbar = 0;

  __shared__ float xs[512];
  __shared__ float xs2[2048];
  __shared__ float red[512];
  __shared__ float lnred[8];

  auto barrier = [&](){
    __syncthreads();
    if (tid == 0){
      __threadfence();
      __hip_atomic_fetch_add(bar, 1u, __ATOMIC_RELAXED, __HIP_MEMORY_SCOPE_AGENT);
      unsigned tgt = (++nbar) * 16u;
      while (__hip_atomic_load(bar, __ATOMIC_RELAXED, __HIP_MEMORY_SCOPE_AGENT) < tgt)
        __builtin_amdgcn_s_sleep(1);
      __threadfence();
    }
    __syncthreads();
  };

  // block-redundant LayerNorm over 512 elems held as (x0,x1) per thread -> out (LDS)
  auto lnorm = [&](float x0, float x1, const float* g, const float* bb, float* out){
    float s = x0 + x1, q = x0*x0 + x1*x1;
    #pragma unroll
    for (int off=32; off>0; off>>=1){ s += __shfl_xor(s, off, 64); q += __shfl_xor(q, off, 64); }
    if ((tid & 63) == 0){ lnred[tid>>6] = s; lnred[4+(tid>>6)] = q; }
    __syncthreads();
    s = lnred[0]+lnred[1]+lnred[2]+lnred[3];
    q = lnred[4]+lnred[5]+lnred[6]+lnred[7];
    float mu = s * (1.f/512.f);
    float rs = rsqrtf(q*(1.f/512.f) - mu*mu + 1e-5f);
    out[tid]     = (x0-mu)*rs*g[tid]     + bb[tid];
    out[tid+256] = (x1-mu)*rs*g[tid+256] + bb[tid+256];
    __syncthreads();
  };

  for (int t=0; t<48; ++t){
    for (int l=0; l<4; ++l){
      // ---------- stage 1: QKV (12 active WGs x 128 outs) ----------
      if (wg < 12){
        if (l == 0){
          xs[tid]     = p.emb_cur[b*512+tid]     + p.pe[t*512+tid];
          xs[tid+256] = p.emb_cur[b*512+tid+256] + p.pe[t*512+tid+256];
          __syncthreads();
        } else {
          float x0 = p.z3[b*512+tid], x1 = p.z3[b*512+tid+256];
          lnorm(x0, x1, p.ln_g + ((l-1)*3+2)*512, p.ln_b + ((l-1)*3+2)*512, xs);
        }
        if (wg == 0){ p.xpost[b*512+tid] = xs[tid]; p.xpost[b*512+tid+256] = xs[tid+256]; }
        int op = tid & 63, kp = tid >> 6;
        int o = wg*128 + op*2;
        const bf16* W = p.WtQKV + (size_t)l*512*1536 + o;
        float a0=0.f, a1=0.f;
        for (int d = kp*128; d < kp*128+128; ++d){
          float w0,w1; bf2(W + (size_t)d*1536, w0, w1);
          float x = xs[d];
          a0 += x*w0; a1 += x*w1;
        }
        red[kp*128+op*2] = a0; red[kp*128+op*2+1] = a1;
        __syncthreads();
        if (tid < 128){
          float v = red[tid] + red[128+tid] + red[256+tid] + red[384+tid];
          int oo = wg*128 + tid;
          v += p.sa_in_b[l*1536 + oo];
          if (oo < 512)       p.qbuf[b*512+oo] = v;
          else if (oo < 1024) p.Kc[((size_t)(l*8+b)*48 + t)*512 + (oo-512)]  = v;
          else                p.Vc[((size_t)(l*8+b)*48 + t)*512 + (oo-1024)] = v;
        }
      }
      barrier();

      // ---------- stage 2: attention (redundant per WG) + out-proj slice ----------
      {
        xs[tid] = p.qbuf[b*512+tid]; xs[tid+256] = p.qbuf[b*512+tid+256];
        __syncthreads();
        int h = tid >> 5, lane = tid & 31;
        const float* Kb = p.Kc + (size_t)(l*8+b)*48*512 + h*64;
        const float* Vb = p.Vc + (size_t)(l*8+b)*48*512 + h*64;
        const float slope = exp2f(-(float)(h+1));
        float s0 = -1e30f, s1 = -1e30f;
        if (lane <= t){
          const float* kr = Kb + (size_t)lane*512;
          float a = 0.f;
          for (int d=0; d<64; ++d) a += xs[h*64+d]*kr[d];
          s0 = a*0.125f - ((t-lane) >= 30 ? slope : 0.f);
        }
        if (lane+32 <= t){
          const float* kr = Kb + (size_t)(lane+32)*512;
          float a = 0.f;
          for (int d=0; d<64; ++d) a += xs[h*64+d]*kr[d];
          s1 = a*0.125f - ((t-lane-32) >= 30 ? slope : 0.f);
        }
        float m = fmaxf(s0, s1);
        #pragma unroll
        for (int off=16; off>0; off>>=1) m = fmaxf(m, __shfl_xor(m, off, 32));
        float e0 = (lane <= t)    ? __expf(s0-m) : 0.f;
        float e1 = (lane+32 <= t) ? __expf(s1-m) : 0.f;
        float sum = e0 + e1;
        #pragma unroll
        for (int off=16; off>0; off>>=1) sum += __shfl_xor(sum, off, 32);
        float inv = 1.f/sum;
        float a0=0.f, a1=0.f;
        for (int j=0; j<=t; ++j){
          float e = (j < 32) ? e0 : e1;
          float pj = __shfl(e, j & 31, 32);
          const float* vr = Vb + (size_t)j*512;
          a0 += pj*vr[lane];
          a1 += pj*vr[lane+32];
        }
        xs2[h*64+lane]    = a0*inv;
        xs2[h*64+lane+32] = a1*inv;
        __syncthreads();
        // out-proj: 16 WGs x 32 outs
        int op = tid & 15, kp = tid >> 4;
        int o = wg*32 + op*2;
        const bf16* W = p.WtO + (size_t)l*512*512 + o;
        float b0=0.f, b1=0.f;
        for (int d = kp*32; d < kp*32+32; ++d){
          float w0,w1; bf2(W + (size_t)d*512, w0, w1);
          float x = xs2[d];
          b0 += x*w0; b1 += x*w1;
        }
        red[kp*32+op*2] = b0; red[kp*32+op*2+1] = b1;
        __syncthreads();
        if (tid < 32){
          float v = 0.f;
          #pragma unroll
          for (int kk=0; kk<16; ++kk) v += red[kk*32+tid];
          int oo = wg*32 + tid;
          p.z1[b*512+oo] = p.xpost[b*512+oo] + v + p.sa_out_b[l*512+oo];
        }
      }
      barrier();

      // ---------- stage 3: LN + cross-const + LN + FF1 (16 WGs x 128 outs) ----------
      {
        float x0 = p.z1[b*512+tid], x1 = p.z1[b*512+tid+256];
        lnorm(x0, x1, p.ln_g + (l*3+0)*512, p.ln_b + (l*3+0)*512, xs);   // xs = u
        const float* xac = p.xa_c + ((size_t)l*384 + b*48 + t)*512;
        float z0 = xs[tid]     + xac[tid];
        float z1v= xs[tid+256] + xac[tid+256];
        __syncthreads();
        lnorm(z0, z1v, p.ln_g + (l*3+1)*512, p.ln_b + (l*3+1)*512, xs);  // xs = u2
        if (wg == 0){ p.u2buf[b*512+tid] = xs[tid]; p.u2buf[b*512+tid+256] = xs[tid+256]; }
        int op = tid & 63, kp = tid >> 6;
        int o = wg*128 + op*2;
        const bf16* W = p.WtF1 + (size_t)l*512*2048 + o;
        float a0=0.f, a1=0.f;
        for (int d = kp*128; d < kp*128+128; ++d){
          float w0,w1; bf2(W + (size_t)d*2048, w0, w1);
          float x = xs[d];
          a0 += x*w0; a1 += x*w1;
        }
        red[kp*128+op*2] = a0; red[kp*128+op*2+1] = a1;
        __syncthreads();
        if (tid < 128){
          float v = red[tid] + red[128+tid] + red[256+tid] + red[384+tid];
          int oo = wg*128 + tid;
          v += p.ff1_b[l*2048 + oo];
          p.hbuf[b*2048 + oo] = fmaxf(v, 0.f);
        }
      }
      barrier();

      // ---------- stage 4: FF2 (16 WGs x 32 outs, Din=2048) ----------
      {
        for (int i=tid; i<2048; i+=256) xs2[i] = p.hbuf[b*2048+i];
        __syncthreads();
        int op = tid & 15, kp = tid >> 4;   // 16 parts x 128
        int o = wg*32 + op*2;
        const bf16* W = p.WtF2 + (size_t)l*2048*512 + o;
        float a0=0.f, a1=0.f;
        for (int f = kp*128; f < kp*128+128; ++f){
          float w0,w1; bf2(W + (size_t)f*512, w0, w1);
          float x = xs2[f];
          a0 += x*w0; a1 += x*w1;
        }
        red[kp*32+op*2] = a0; red[kp*32+op*2+1] = a1;
        __syncthreads();
        if (tid < 32){
          float v = 0.f;
          #pragma unroll
          for (int kk=0; kk<16; ++kk) v += red[kk*32+tid];
          int oo = wg*32 + tid;
          p.z3[b*512+oo] = p.u2buf[b*512+oo] + v + p.ff2_b[l*512+oo];
        }
      }
      barrier();
    } // layers

    // ---------- step A: final LN + mmr row -> dec_out, then 'new' (WG0 only) ----------
    if (wg == 0){
      float x0 = p.z3[b*512+tid], x1 = p.z3[b*512+tid+256];
      lnorm(x0, x1, p.ln_g + 11*512, p.ln_b + 11*512, xs);
      int mi = tid & 63, kp = tid >> 6;
      float a = 0.f;
      for (int d = kp*128; d < kp*128+128; ++d) a += xs[d]*p.Wt_mmr[(size_t)d*64+mi];
      red[kp*64+mi] = a;
      __syncthreads();
      if (tid < 64){
        float v = red[tid] + red[64+tid] + red[128+tid] + red[192+tid] + p.mmr_b[tid];
        p.dec_out[((size_t)b*48 + t)*64 + tid] = v;
        xs2[tid] = v;
      }
      __syncthreads();
      float n0=0.f, n1=0.f;
      for (int m=0; m<64; ++m){
        float x = xs2[m];
        n0 += x*p.Wt_mm[(size_t)m*512+tid];
        n1 += x*p.Wt_mm[(size_t)m*512+tid+256];
      }
      p.newb[b*512+tid]     = n0 + p.mm_b[tid];
      p.newb[b*512+tid+256] = n1 + p.mm_b[tid+256];
    }
    barrier();

    // ---------- step B: next emb = [new, sel_t] @ Wt_se + se_b + style ----------
    {
      int op = tid & 15, kp = tid >> 4;   // 16 parts x 64 (Din=1024)
      int o = wg*32 + op*2;
      const float* selr = p.sel + ((size_t)b*48 + t)*512;
      float a0=0.f, a1=0.f;
      for (int d = kp*64; d < kp*64+64; ++d){
        float x = (d < 512) ? p.newb[b*512+d] : selr[d-512];
        float2 w = *reinterpret_cast<const float2*>(&p.Wt_se[(size_t)d*512 + o]);
        a0 += x*w.x; a1 += x*w.y;
      }
      red[kp*32+op*2] = a0; red[kp*32+op*2+1] = a1;
      __syncthreads();
      if (tid < 32){
        float v = 0.f;
        #pragma unroll
        for (int kk=0; kk<16; ++kk) v += red[kk*32+tid];
        int oo = wg*32 + tid;
        p.emb_cur[b*512+oo] = v + p.se_b[oo] + p.style[b*512+oo];
      }
    }
    barrier();
  } // t
}

// ---------------- host ----------------
extern "C" void kernel_launch(void* const* d_in, const int* in_sizes, int n_in,
                              void* d_out, int out_size, void* d_ws, size_t ws_size,
                              hipStream_t stream){
  (void)in_sizes; (void)n_in; (void)out_size; (void)ws_size;
  const float* content = (const float*)d_in[0];
  const float* style   = (const float*)d_in[1];
  const float* shid    = (const float*)d_in[2];
  const float* init_st = (const float*)d_in[3];
  const float* ca_in_w = (const float*)d_in[4];
  const float* ca_in_b = (const float*)d_in[5];
  const float* ca_out_w= (const float*)d_in[6];
  const float* ca_out_b= (const float*)d_in[7];
  const float* se_w    = (const float*)d_in[8];
  const float* se_b    = (const float*)d_in[9];
  const float* mm_w    = (const float*)d_in[10];
  const float* mm_b    = (const float*)d_in[11];
  const float* mmr_w   = (const float*)d_in[12];
  const float* mmr_b   = (const float*)d_in[13];
  const float* sa_in_w = (const float*)d_in[14];
  const float* sa_in_b = (const float*)d_in[15];
  const float* sa_out_w= (const float*)d_in[16];
  const float* sa_out_b= (const float*)d_in[17];
  const float* xa_in_w = (const float*)d_in[18];
  const float* xa_in_b = (const float*)d_in[19];
  const float* xa_out_w= (const float*)d_in[20];
  const float* xa_out_b= (const float*)d_in[21];
  const float* ff1_w   = (const float*)d_in[22];
  const float* ff1_b   = (const float*)d_in[23];
  const float* ff2_w   = (const float*)d_in[24];
  const float* ff2_b   = (const float*)d_in[25];
  const float* ln_g    = (const float*)d_in[26];
  const float* ln_b    = (const float*)d_in[27];

  float* out = (float*)d_out;
  float* dec_out = out;            // (8,48,64)
  float* sel = out + 8*48*64;      // (8,48,512)

  char* base = (char*)d_ws;
  size_t cur = 0;
  auto alloc = [&](size_t bytes)->char*{
    char* pt = base + cur;
    cur += (bytes + 255) & ~(size_t)255;
    return pt;
  };
  unsigned* bar   = (unsigned*)alloc(8*64*4);
  bf16* WtQKV = (bf16*)alloc((size_t)4*512*1536*2);
  bf16* WtO   = (bf16*)alloc((size_t)4*512*512*2);
  bf16* WtF1  = (bf16*)alloc((size_t)4*512*2048*2);
  bf16* WtF2  = (bf16*)alloc((size_t)4*2048*512*2);
  float* Wt_mm    = (float*)alloc((size_t)64*512*4);
  float* Wt_mmr   = (float*)alloc((size_t)512*64*4);
  float* Wt_se    = (float*)alloc((size_t)1024*512*4);
  float* Wt_ca_in = (float*)alloc((size_t)512*1536*4);
  float* Wt_ca_out= (float*)alloc((size_t)512*512*4);
  float* Wt_xa_v  = (float*)alloc((size_t)4*512*512*4);
  float* Wt_xa_o  = (float*)alloc((size_t)4*512*512*4);
  float* xa_c  = (float*)alloc((size_t)4*384*512*4);
  float* Kc    = (float*)alloc((size_t)4*8*48*512*4);
  float* Vc    = (float*)alloc((size_t)4*8*48*512*4);
  float* pe    = (float*)alloc((size_t)48*512*4);
  float* qh    = (float*)alloc((size_t)384*512*4);
  float* khb   = (float*)alloc((size_t)512*512*4);
  float* vhb   = (float*)alloc((size_t)512*512*4);
  float* attno = (float*)alloc((size_t)384*512*4);
  float* xtmp  = (float*)alloc((size_t)384*512*4);
  float* catb  = (float*)alloc((size_t)8*1024*4);
  float* embt  = (float*)alloc((size_t)8*512*4);
  float* emb_cur=(float*)alloc((size_t)8*512*4);
  float* qbuf  = (float*)alloc((size_t)8*512*4);
  float* z1b   = (float*)alloc((size_t)8*512*4);
  float* z3b   = (float*)alloc((size_t)8*512*4);
  float* hbuf  = (float*)alloc((size_t)8*2048*4);
  float* u2buf = (float*)alloc((size_t)8*512*4);
  float* xpost = (float*)alloc((size_t)8*512*4);
  float* newb  = (float*)alloc((size_t)8*512*4);

  hipMemsetAsync(bar, 0, 8*64*4, stream);

  dim3 tb(32,8);
  for (int l=0; l<4; ++l){
    k_transpose<bf16><<<dim3(16,48), tb, 0, stream>>>(sa_in_w + (size_t)l*1536*512, WtQKV + (size_t)l*512*1536, 1536, 512);
    k_transpose<bf16><<<dim3(16,16), tb, 0, stream>>>(sa_out_w + (size_t)l*512*512,  WtO   + (size_t)l*512*512,  512, 512);
    k_transpose<bf16><<<dim3(16,64), tb, 0, stream>>>(ff1_w   + (size_t)l*2048*512, WtF1  + (size_t)l*512*2048, 2048, 512);
    k_transpose<bf16><<<dim3(64,16), tb, 0, stream>>>(ff2_w   + (size_t)l*512*2048, WtF2  + (size_t)l*2048*512, 512, 2048);
    k_transpose<float><<<dim3(16,16), tb, 0, stream>>>(xa_in_w + (size_t)l*1536*512 + (size_t)1024*512, Wt_xa_v + (size_t)l*512*512, 512, 512);
    k_transpose<float><<<dim3(16,16), tb, 0, stream>>>(xa_out_w + (size_t)l*512*512, Wt_xa_o + (size_t)l*512*512, 512, 512);
  }
  k_transpose<float><<<dim3(16,48), tb, 0, stream>>>(ca_in_w,  Wt_ca_in, 1536, 512);
  k_transpose<float><<<dim3(16,16), tb, 0, stream>>>(ca_out_w, Wt_ca_out, 512, 512);
  k_transpose<float><<<dim3(32,16), tb, 0, stream>>>(se_w,  Wt_se, 512, 1024);
  k_transpose<float><<<dim3(2,16),  tb, 0, stream>>>(mm_w,  Wt_mm, 512, 64);
  k_transpose<float><<<dim3(16,2),  tb, 0, stream>>>(mmr_w, Wt_mmr, 64, 512);

  k_pe<<<96, 256, 0, stream>>>(pe);

  // sel = MHA(content, style_hiddens, style_hiddens), nh=1
  k_linear<<<dim3(4,48), 256, 0, stream>>>(content, 512, Wt_ca_in,        1536, ca_in_b,        qh,  512, 512, 512);
  k_linear<<<dim3(4,64), 256, 0, stream>>>(shid,    512, Wt_ca_in + 512,  1536, ca_in_b + 512,  khb, 512, 512, 512);
  k_linear<<<dim3(4,64), 256, 0, stream>>>(shid,    512, Wt_ca_in + 1024, 1536, ca_in_b + 1024, vhb, 512, 512, 512);
  k_sel_attn<<<384, 256, 0, stream>>>(qh, khb, vhb, attno);
  k_linear<<<dim3(4,48), 256, 0, stream>>>(attno, 512, Wt_ca_out, 512, ca_out_b, sel, 512, 512, 512);

  // cross-attn constants per layer: (mem @ wv.T + bv) @ out_w.T + out_b
  for (int l=0; l<4; ++l){
    k_linear<<<dim3(4,48), 256, 0, stream>>>(content, 512, Wt_xa_v + (size_t)l*512*512, 512,
                                             xa_in_b + l*1536 + 1024, xtmp, 512, 512, 512);
    k_linear<<<dim3(4,48), 256, 0, stream>>>(xtmp, 512, Wt_xa_o + (size_t)l*512*512, 512,
                                             xa_out_b + l*512, xa_c + (size_t)l*384*512, 512, 512, 512);
  }

  // emb0 = concat(init_state@mm_w.T+mm_b, sel[:,0]) @ se_w.T + se_b + style
  k_linear<<<dim3(4,1), 256, 0, stream>>>(init_st, 64, Wt_mm, 512, mm_b, catb, 1024, 512, 64);
  k_cat_tail<<<16, 256, 0, stream>>>(sel, catb);
  k_linear<<<dim3(4,1), 256, 0, stream>>>(catb, 1024, Wt_se, 512, se_b, embt, 512, 512, 1024);
  k_add_style<<<16, 256, 0, stream>>>(embt, style, emb_cur);

  DP p;
  p.bar = bar;
  p.emb_cur = emb_cur; p.qbuf = qbuf; p.z1 = z1b; p.z3 = z3b; p.hbuf = hbuf;
  p.u2buf = u2buf; p.xpost = xpost; p.newb = newb;
  p.Kc = Kc; p.Vc = Vc; p.xa_c = xa_c; p.pe = pe;
  p.WtQKV = WtQKV; p.WtO = WtO; p.WtF1 = WtF1; p.WtF2 = WtF2;
  p.Wt_mmr = Wt_mmr; p.Wt_mm = Wt_mm; p.Wt_se = Wt_se;
  p.sa_in_b = sa_in_b; p.sa_out_b = sa_out_b; p.ff1_b = ff1_b; p.ff2_b = ff2_b;
  p.mmr_b = mmr_b; p.mm_b = mm_b; p.se_b = se_b; p.ln_g = ln_g; p.ln_b = ln_b;
  p.style = style; p.sel = sel; p.dec_out = dec_out;

  // plain launch: 128 blocks x 256 threads, <=1 block/CU on 256 CUs => all
  // co-resident; spin barrier safe without cooperative launch (which is not
  // graph-capturable and silently no-ops under the harness's capture).
  k_decode<<<dim3(128), dim3(256), 0, stream>>>(p);
}

// Round 3
// 6770.574 us; speedup vs baseline: 4.1794x; 4.1794x over previous
//
#include <hip/hip_runtime.h>
#include <hip/hip_bf16.h>

// Problem constants: B=8, F=48, S=64, D=512, NH=8, L=4, DFF=2048, M=64, PERIOD=30
using bf16 = __hip_bfloat16;

// ---------------- helpers ----------------
__device__ inline void storeT(float* d, float v){ *d = v; }
__device__ inline void storeT(bf16* d, float v){ *d = __float2bfloat16(v); }

__device__ inline float aload(const float* p){
  return __hip_atomic_load(p, __ATOMIC_RELAXED, __HIP_MEMORY_SCOPE_AGENT);
}
__device__ inline void astore(float* p, float v){
  __hip_atomic_store(p, v, __ATOMIC_RELAXED, __HIP_MEMORY_SCOPE_AGENT);
}

// dot of n (multiple of 8) bf16 weights (contiguous row) with fp32 x (LDS)
__device__ inline float dot_bf16(const ushort* wrow, const float* x, int n){
  const uint4* w4 = (const uint4*)wrow;
  float acc = 0.f;
  for (int i=0; i<(n>>3); ++i){
    uint4 w = w4[i];
    const float* xp = x + i*8;
    acc = fmaf(__uint_as_float(w.x<<16),         xp[0], acc);
    acc = fmaf(__uint_as_float(w.x&0xffff0000u), xp[1], acc);
    acc = fmaf(__uint_as_float(w.y<<16),         xp[2], acc);
    acc = fmaf(__uint_as_float(w.y&0xffff0000u), xp[3], acc);
    acc = fmaf(__uint_as_float(w.z<<16),         xp[4], acc);
    acc = fmaf(__uint_as_float(w.z&0xffff0000u), xp[5], acc);
    acc = fmaf(__uint_as_float(w.w<<16),         xp[6], acc);
    acc = fmaf(__uint_as_float(w.w&0xffff0000u), xp[7], acc);
  }
  return acc;
}
// dot of n (multiple of 4) fp32 weights with fp32 x
__device__ inline float dot_f32(const float* wrow, const float* x, int n){
  const float4* w4 = (const float4*)wrow;
  float acc = 0.f;
  for (int i=0; i<(n>>2); ++i){
    float4 w = w4[i];
    const float* xp = x + i*4;
    acc = fmaf(w.x, xp[0], acc); acc = fmaf(w.y, xp[1], acc);
    acc = fmaf(w.z, xp[2], acc); acc = fmaf(w.w, xp[3], acc);
  }
  return acc;
}

// ---------------- transpose (src R x C -> dst C x R), cast to T ----------------
template<typename T>
__global__ void k_transpose(const float* __restrict__ src, T* __restrict__ dst, int R, int C){
  __shared__ float tile[32][33];
  int cb = blockIdx.x*32, rb = blockIdx.y*32;
  int tx = threadIdx.x, ty = threadIdx.y;   // blockDim (32,8)
  for (int i=ty; i<32; i+=8) tile[i][tx] = src[(size_t)(rb+i)*C + cb+tx];
  __syncthreads();
  for (int i=ty; i<32; i+=8) storeT(&dst[(size_t)(cb+i)*R + rb+tx], tile[tx][i]);
}

// cast fp32 -> bf16 (same layout)
__global__ void k_castbf(const float* __restrict__ s, bf16* __restrict__ d, int n){
  int i = blockIdx.x*256 + threadIdx.x;
  if (i < n) d[i] = __float2bfloat16(s[i]);
}

// ---------------- generic linear: C[r,o] = sum_d A[r,d]*Wt[d,o] + bias[o] ----------------
__global__ void k_linear(const float* __restrict__ A, int lda,
                         const float* __restrict__ Wt, int ldw,
                         const float* __restrict__ bias,
                         float* __restrict__ C, int ldc,
                         int O, int Din){
  __shared__ float xs[8*1024];
  __shared__ float red[4096];
  int tid = threadIdx.x;
  int r0 = blockIdx.y*8;
  for (int idx=tid; idx<8*Din; idx+=256){
    int ri = idx / Din, d = idx - ri*Din;
    xs[idx] = A[(size_t)(r0+ri)*lda + d];
  }
  __syncthreads();
  int op = tid & 63, kp = tid >> 6;
  int o = blockIdx.x*128 + op*2;
  int dq = Din >> 2;
  float a0[8] = {0,0,0,0,0,0,0,0}, a1[8] = {0,0,0,0,0,0,0,0};
  for (int d = kp*dq; d < kp*dq+dq; ++d){
    float2 w = *reinterpret_cast<const float2*>(&Wt[(size_t)d*ldw + o]);
    #pragma unroll
    for (int ri=0; ri<8; ++ri){ float x = xs[ri*Din+d]; a0[ri] += x*w.x; a1[ri] += x*w.y; }
  }
  #pragma unroll
  for (int ri=0; ri<8; ++ri){
    red[((kp*64+op)*8+ri)*2]   = a0[ri];
    red[((kp*64+op)*8+ri)*2+1] = a1[ri];
  }
  __syncthreads();
  for (int idx = tid; idx < 1024; idx += 256){
    int ri = idx >> 7, oc = idx & 127;
    int opp = oc >> 1, c = oc & 1;
    float v = red[((0*64+opp)*8+ri)*2 + c] + red[((1*64+opp)*8+ri)*2 + c]
            + red[((2*64+opp)*8+ri)*2 + c] + red[((3*64+opp)*8+ri)*2 + c];
    int oo = blockIdx.x*128 + oc;
    if (bias) v += bias[oo];
    C[(size_t)(r0+ri)*ldc + oo] = v;
  }
}

// ---------------- PE table ----------------
__global__ void k_pe(float* __restrict__ pe){
  int idx = blockIdx.x*256 + threadIdx.x;  // 48*512
  int t = idx >> 9, d = idx & 511;
  int p = t % 30;
  int i2 = d & ~1;
  float div = __expf(-(float)i2 * (9.210340371976184f/512.f));
  float ang = (float)p * div;
  pe[idx] = (d & 1) ? cosf(ang) : sinf(ang);
}

// ---------------- sel attention (nh=1) ----------------
__global__ void k_sel_attn(const float* __restrict__ qh, const float* __restrict__ kh,
                           const float* __restrict__ vh, float* __restrict__ o){
  int bf = blockIdx.x;           // b*48+f
  int b  = bf / 48;
  int tid = threadIdx.x;
  __shared__ float qs[512];
  __shared__ float ps[64];
  qs[tid] = qh[(size_t)bf*512 + tid];
  qs[tid+256] = qh[(size_t)bf*512 + tid + 256];
  __syncthreads();
  if (tid < 64){
    const float* kr = kh + (size_t)(b*64+tid)*512;
    float a = 0.f;
    for (int d=0; d<512; ++d) a += qs[d]*kr[d];
    ps[tid] = a * 0.04419417382415922f;
  }
  __syncthreads();
  if (tid == 0){
    float m = -1e30f;
    for (int j=0;j<64;++j) m = fmaxf(m, ps[j]);
    float s = 0.f;
    for (int j=0;j<64;++j){ float e = __expf(ps[j]-m); ps[j]=e; s+=e; }
    float iv = 1.f/s;
    for (int j=0;j<64;++j) ps[j] *= iv;
  }
  __syncthreads();
  float a0=0.f, a1=0.f;
  for (int j=0;j<64;++j){
    const float* vr = vh + (size_t)(b*64+j)*512;
    float pj = ps[j];
    a0 += pj*vr[tid]; a1 += pj*vr[tid+256];
  }
  o[(size_t)bf*512+tid] = a0;
  o[(size_t)bf*512+tid+256] = a1;
}

// ---------------- tiny glue ----------------
__global__ void k_cat_tail(const float* __restrict__ sel, float* __restrict__ cat){
  int idx = blockIdx.x*256 + threadIdx.x;  // 8*512
  int b = idx >> 9, d = idx & 511;
  cat[b*1024 + 512 + d] = sel[(size_t)(b*48)*512 + d];
}
__global__ void k_add_style(const float* __restrict__ embt, const float* __restrict__ style,
                            float* __restrict__ emb){
  int idx = blockIdx.x*256 + threadIdx.x;  // 8*512 -> emb slot t=0
  emb[idx] = embt[idx] + style[idx];
}

// ---------------- persistent decode kernel ----------------
// 128 blocks (<=256 CUs -> all co-resident), one batch per 16 WGs.
// role = (i&7)*2 + ((i>>3)&1): blocks sharing an XCD (i%8) share 2 roles,
// keeping the per-XCD weight working set ~3.4 MB (< 4 MB L2).
// NO fences anywhere: all cross-WG data moves via agent-scope relaxed
// atomics (coherence point, bypass L2); weights stay L2-resident.
struct DP {
  unsigned* fl;        // flags: [b][t][stage 0..8][role]
  float* z;            // [b][t][8 slots][512] accumulators (memset 0)
  float* emb;          // [t 0..48][b][512] (memset 0; slot0 from precompute)
  float* Vpriv;        // per-WG private V cache [wg][l][48][64]
  const bf16 *Wqkv, *Wo, *Wf1, *Wf2;   // bf16, original [out][in] layout
  const float *xa_c, *pe;
  const float *sa_in_b, *sa_out_b, *ff1_b, *ff2_b;
  const float *mmr_w, *mmr_b, *mm_w, *mm_b, *se_w, *se_b;
  const float *ln_g, *ln_b, *style, *sel;
  float* dec_out;
};

__launch_bounds__(256, 1)
__global__ void k_decode(DP p){
  const int tid = threadIdx.x;
  const int i = blockIdx.x;
  const int role = ((i & 7) << 1) | ((i >> 3) & 1);
  const int b = i >> 4;
  const int h = role >> 1, half = role & 1;
  const float slope = exp2f(-(float)(h+1));

  __shared__ float kc[4*48*65];   // K cache, fp32, pad 65 vs bank conflicts
  __shared__ float xs[512];
  __shared__ float red[512];
  __shared__ float qs[64], ps[64], an[64], d64[64];
  __shared__ float hs[128];
  __shared__ float ns[512];
  __shared__ float lnred[8];

  float* Vp = p.Vpriv + (size_t)i*4*48*64;
  unsigned* flb = p.fl + (size_t)b*48*9*16;
  float* zb = p.z + (size_t)b*48*8*512;

  auto wait16 = [&](int t, int s){
    unsigned* f = flb + (size_t)(t*9+s)*16;
    if (tid < 16){
      while (__hip_atomic_load(&f[tid], __ATOMIC_RELAXED, __HIP_MEMORY_SCOPE_AGENT) == 0u)
        __builtin_amdgcn_s_sleep(2);
    }
    __syncthreads();
  };
  auto post = [&](int t, int s){
    __syncthreads();   // all waves drain vmcnt (atomics complete) at barrier
    if (tid == 0)
      __hip_atomic_store(&flb[(size_t)(t*9+s)*16 + role], 1u,
                         __ATOMIC_RELEASE, __HIP_MEMORY_SCOPE_AGENT);
  };
  auto lnorm = [&](float x0, float x1, const float* g, const float* bb, float* out){
    float s = x0 + x1, q = x0*x0 + x1*x1;
    #pragma unroll
    for (int off=32; off>0; off>>=1){ s += __shfl_xor(s, off, 64); q += __shfl_xor(q, off, 64); }
    if ((tid & 63) == 0){ lnred[tid>>6] = s; lnred[4+(tid>>6)] = q; }
    __syncthreads();
    s = lnred[0]+lnred[1]+lnred[2]+lnred[3];
    q = lnred[4]+lnred[5]+lnred[6]+lnred[7];
    float mu = s * (1.f/512.f);
    float rs = rsqrtf(q*(1.f/512.f) - mu*mu + 1e-5f);
    out[tid]     = (x0-mu)*rs*g[tid]     + bb[tid];
    out[tid+256] = (x1-mu)*rs*g[tid+256] + bb[tid+256];
    __syncthreads();
  };

  for (int t=0; t<48; ++t){
    for (int l=0; l<4; ++l){
      // ===== stage A: x prep + QKV (own head) + attention + O-partial =====
      if (l == 0){ if (t > 0) wait16(t-1, 8); }
      else wait16(t, (l-1)*2+1);

      if (l == 0){
        float e0 = aload(p.emb + ((size_t)t*8+b)*512 + tid);
        float e1 = aload(p.emb + ((size_t)t*8+b)*512 + tid + 256);
        xs[tid]     = e0 + p.pe[t*512+tid];
        xs[tid+256] = e1 + p.pe[t*512+tid+256];
        __syncthreads();
      } else {
        float* zs = zb + ((size_t)t*8 + (l-1)*2+1)*512;
        float z0 = aload(zs+tid), z1 = aload(zs+tid+256);
        lnorm(z0, z1, p.ln_g + ((l-1)*3+2)*512, p.ln_b + ((l-1)*3+2)*512, xs);
      }
      // QKV for head h: threads 0..63 q, 64..127 k, 128..191 v
      if (tid < 192){
        int sec = tid >> 6, dch = tid & 63;
        int row = sec*512 + h*64 + dch;
        float acc = dot_bf16((const ushort*)p.Wqkv + ((size_t)l*1536+row)*512, xs, 512)
                  + p.sa_in_b[l*1536+row];
        if (sec == 0) qs[dch] = acc;
        else if (sec == 1) kc[(l*48+t)*65 + dch] = acc;
        else Vp[((size_t)l*48+t)*64 + dch] = acc;   // WG-private, plain cached
      }
      __syncthreads();
      // scores + softmax (wave 0)
      if (tid < 64){
        float sc = -1e30f;
        if (tid <= t){
          float a = 0.f;
          const float* kr = &kc[(l*48+tid)*65];
          #pragma unroll
          for (int d=0; d<64; ++d) a = fmaf(qs[d], kr[d], a);
          sc = a*0.125f - ((t-tid) >= 30 ? slope : 0.f);
        }
        float m = sc;
        #pragma unroll
        for (int off=32; off>0; off>>=1) m = fmaxf(m, __shfl_xor(m, off, 64));
        float e = (tid <= t) ? __expf(sc-m) : 0.f;
        float s = e;
        #pragma unroll
        for (int off=32; off>0; off>>=1) s += __shfl_xor(s, off, 64);
        ps[tid] = e / s;
      }
      __syncthreads();
      // PV: d = tid&63, j-quarter = tid>>6
      {
        int d = tid & 63, jq = tid >> 6;
        float a = 0.f;
        for (int j=jq*12; j<jq*12+12; ++j)
          if (j <= t) a = fmaf(ps[j], Vp[((size_t)l*48+j)*64 + d], a);
        red[tid] = a;
      }
      __syncthreads();
      if (tid < 64) an[tid] = red[tid]+red[64+tid]+red[128+tid]+red[192+tid];
      __syncthreads();
      // O-partial over this head's 64 dims, out-half per `half`
      {
        int o = half*256 + tid;
        float acc = dot_bf16((const ushort*)p.Wo + (((size_t)l*512+o)*512 + h*64), an, 64);
        if (h == 0) acc += xs[o] + p.sa_out_b[l*512+o];  // residual+bias once
        unsafeAtomicAdd(zb + ((size_t)t*8 + l*2)*512 + o, acc);
      }
      post(t, l*2);

      // ===== stage B: LN + cross-const + LN + FF1 slice + FF2 partial =====
      wait16(t, l*2);
      {
        float* zs = zb + ((size_t)t*8 + l*2)*512;
        float z0 = aload(zs+tid), z1 = aload(zs+tid+256);
        lnorm(z0, z1, p.ln_g + (l*3)*512, p.ln_b + (l*3)*512, xs);
        const float* xac = p.xa_c + ((size_t)l*384 + b*48 + t)*512;
        float u0 = xs[tid]     + xac[tid];
        float u1 = xs[tid+256] + xac[tid+256];
        lnorm(u0, u1, p.ln_g + (l*3+1)*512, p.ln_b + (l*3+1)*512, xs);  // xs = u2
      }
      {
        int oo = tid & 127, hh = tid >> 7;
        int row = role*128 + oo;
        red[tid] = dot_bf16((const ushort*)p.Wf1 + ((size_t)l*2048+row)*512 + hh*256,
                            xs + hh*256, 256);
      }
      __syncthreads();
      if (tid < 128){
        float v = red[tid] + red[128+tid] + p.ff1_b[l*2048 + role*128 + tid];
        hs[tid] = fmaxf(v, 0.f);
      }
      __syncthreads();
      {
        float a0 = dot_bf16((const ushort*)p.Wf2 + ((size_t)l*512+tid)*2048 + role*128, hs, 128);
        float a1 = dot_bf16((const ushort*)p.Wf2 + ((size_t)l*512+tid+256)*2048 + role*128, hs, 128);
        if (role == 0){
          a0 += xs[tid]     + p.ff2_b[l*512+tid];
          a1 += xs[tid+256] + p.ff2_b[l*512+tid+256];
        }
        float* zs = zb + ((size_t)t*8 + l*2+1)*512;
        unsafeAtomicAdd(zs+tid, a0);
        unsafeAtomicAdd(zs+tid+256, a1);
      }
      post(t, l*2+1);
    } // layers

    // ===== tail: LN + mmr -> dec_out, mm -> new, se -> next emb =====
    wait16(t, 7);
    {
      float* zs = zb + ((size_t)t*8 + 7)*512;
      float z0 = aload(zs+tid), z1 = aload(zs+tid+256);
      lnorm(z0, z1, p.ln_g + 11*512, p.ln_b + 11*512, xs);
    }
    {
      int o = tid & 63, kq = tid >> 6;
      red[tid] = dot_f32(p.mmr_w + (size_t)o*512 + kq*128, xs + kq*128, 128);
    }
    __syncthreads();
    if (tid < 64){
      float v = red[tid]+red[64+tid]+red[128+tid]+red[192+tid] + p.mmr_b[tid];
      d64[tid] = v;
      if (role == 0) p.dec_out[((size_t)b*48+t)*64 + tid] = v;
    }
    __syncthreads();
    {
      ns[tid]     = dot_f32(p.mm_w + (size_t)tid*64,       d64, 64) + p.mm_b[tid];
      ns[tid+256] = dot_f32(p.mm_w + (size_t)(tid+256)*64, d64, 64) + p.mm_b[tid+256];
    }
    __syncthreads();
    {
      int oo = tid & 31, part = tid >> 5;   // 8 parts x 128
      int o = role*32 + oo;
      float acc;
      if (part < 4)
        acc = dot_f32(p.se_w + (size_t)o*1024 + part*128, ns + part*128, 128);
      else
        acc = dot_f32(p.se_w + (size_t)o*1024 + part*128,
                      p.sel + ((size_t)b*48+t)*512 + (part-4)*128, 128);
      red[tid] = acc;
    }
    __syncthreads();
    if (tid < 32){
      float v = 0.f;
      #pragma unroll
      for (int k8=0; k8<8; ++k8) v += red[k8*32+tid];
      int o = role*32 + tid;
      v += p.se_b[o] + p.style[(size_t)b*512+o];
      astore(p.emb + ((size_t)(t+1)*8+b)*512 + o, v);
    }
    post(t, 8);
  } // t
}

// ---------------- host ----------------
extern "C" void kernel_launch(void* const* d_in, const int* in_sizes, int n_in,
                              void* d_out, int out_size, void* d_ws, size_t ws_size,
                              hipStream_t stream){
  (void)in_sizes; (void)n_in; (void)out_size; (void)ws_size;
  const float* content = (const float*)d_in[0];
  const float* style   = (const float*)d_in[1];
  const float* shid    = (const float*)d_in[2];
  const float* init_st = (const float*)d_in[3];
  const float* ca_in_w = (const float*)d_in[4];
  const float* ca_in_b = (const float*)d_in[5];
  const float* ca_out_w= (const float*)d_in[6];
  const float* ca_out_b= (const float*)d_in[7];
  const float* se_w    = (const float*)d_in[8];
  const float* se_b    = (const float*)d_in[9];
  const float* mm_w    = (const float*)d_in[10];
  const float* mm_b    = (const float*)d_in[11];
  const float* mmr_w   = (const float*)d_in[12];
  const float* mmr_b   = (const float*)d_in[13];
  const float* sa_in_w = (const float*)d_in[14];
  const float* sa_in_b = (const float*)d_in[15];
  const float* sa_out_w= (const float*)d_in[16];
  const float* sa_out_b= (const float*)d_in[17];
  const float* xa_in_w = (const float*)d_in[18];
  const float* xa_in_b = (const float*)d_in[19];
  const float* xa_out_w= (const float*)d_in[20];
  const float* xa_out_b= (const float*)d_in[21];
  const float* ff1_w   = (const float*)d_in[22];
  const float* ff1_b   = (const float*)d_in[23];
  const float* ff2_w   = (const float*)d_in[24];
  const float* ff2_b   = (const float*)d_in[25];
  const float* ln_g    = (const float*)d_in[26];
  const float* ln_b    = (const float*)d_in[27];

  float* out = (float*)d_out;
  float* dec_out = out;            // (8,48,64)
  float* sel = out + 8*48*64;      // (8,48,512)

  char* base = (char*)d_ws;
  size_t cur = 0;
  auto alloc = [&](size_t bytes)->char*{
    char* pt = base + cur;
    cur += (bytes + 255) & ~(size_t)255;
    return pt;
  };
  // --- contiguous zero-init region: flags | z accum | emb slots ---
  unsigned* fl  = (unsigned*)alloc((size_t)8*48*9*16*4);          // 221184 B
  float* zacc   = (float*)alloc((size_t)8*48*8*512*4);            // 6.29 MB
  float* emb    = (float*)alloc((size_t)49*8*512*4);              // 0.80 MB
  size_t zero_span = cur;                                          // from fl
  // --- rest of workspace ---
  float* Vpriv  = (float*)alloc((size_t)128*4*48*64*4);           // 6.3 MB
  bf16* WqkvB = (bf16*)alloc((size_t)4*1536*512*2);
  bf16* WoB   = (bf16*)alloc((size_t)4*512*512*2);
  bf16* Wf1B  = (bf16*)alloc((size_t)4*2048*512*2);
  bf16* Wf2B  = (bf16*)alloc((size_t)4*512*2048*2);
  float* Wt_mm    = (float*)alloc((size_t)64*512*4);
  float* Wt_se    = (float*)alloc((size_t)1024*512*4);
  float* Wt_ca_in = (float*)alloc((size_t)512*1536*4);
  float* Wt_ca_out= (float*)alloc((size_t)512*512*4);
  float* Wt_xa_v  = (float*)alloc((size_t)4*512*512*4);
  float* Wt_xa_o  = (float*)alloc((size_t)4*512*512*4);
  float* xa_c  = (float*)alloc((size_t)4*384*512*4);
  float* pe    = (float*)alloc((size_t)48*512*4);
  float* qh    = (float*)alloc((size_t)384*512*4);
  float* khb   = (float*)alloc((size_t)512*512*4);
  float* vhb   = (float*)alloc((size_t)512*512*4);
  float* attno = (float*)alloc((size_t)384*512*4);
  float* xtmp  = (float*)alloc((size_t)384*512*4);
  float* catb  = (float*)alloc((size_t)8*1024*4);
  float* embt  = (float*)alloc((size_t)8*512*4);

  hipMemsetAsync(fl, 0, zero_span, stream);

  dim3 tb(32,8);
  // bf16 casts (original [out][in] layout, contiguous rows)
  k_castbf<<<(4*1536*512+255)/256, 256, 0, stream>>>(sa_in_w, WqkvB, 4*1536*512);
  k_castbf<<<(4*512*512+255)/256, 256, 0, stream>>>(sa_out_w, WoB,  4*512*512);
  k_castbf<<<(4*2048*512+255)/256, 256, 0, stream>>>(ff1_w,  Wf1B, 4*2048*512);
  k_castbf<<<(4*512*2048+255)/256, 256, 0, stream>>>(ff2_w,  Wf2B, 4*512*2048);
  // fp32 transposes for the precompute GEMMs
  for (int l=0; l<4; ++l){
    k_transpose<float><<<dim3(16,16), tb, 0, stream>>>(xa_in_w + (size_t)l*1536*512 + (size_t)1024*512, Wt_xa_v + (size_t)l*512*512, 512, 512);
    k_transpose<float><<<dim3(16,16), tb, 0, stream>>>(xa_out_w + (size_t)l*512*512, Wt_xa_o + (size_t)l*512*512, 512, 512);
  }
  k_transpose<float><<<dim3(16,48), tb, 0, stream>>>(ca_in_w,  Wt_ca_in, 1536, 512);
  k_transpose<float><<<dim3(16,16), tb, 0, stream>>>(ca_out_w, Wt_ca_out, 512, 512);
  k_transpose<float><<<dim3(32,16), tb, 0, stream>>>(se_w,  Wt_se, 512, 1024);
  k_transpose<float><<<dim3(2,16),  tb, 0, stream>>>(mm_w,  Wt_mm, 512, 64);

  k_pe<<<96, 256, 0, stream>>>(pe);

  // sel = MHA(content, style_hiddens, style_hiddens), nh=1
  k_linear<<<dim3(4,48), 256, 0, stream>>>(content, 512, Wt_ca_in,        1536, ca_in_b,        qh,  512, 512, 512);
  k_linear<<<dim3(4,64), 256, 0, stream>>>(shid,    512, Wt_ca_in + 512,  1536, ca_in_b + 512,  khb, 512, 512, 512);
  k_linear<<<dim3(4,64), 256, 0, stream>>>(shid,    512, Wt_ca_in + 1024, 1536, ca_in_b + 1024, vhb, 512, 512, 512);
  k_sel_attn<<<384, 256, 0, stream>>>(qh, khb, vhb, attno);
  k_linear<<<dim3(4,48), 256, 0, stream>>>(attno, 512, Wt_ca_out, 512, ca_out_b, sel, 512, 512, 512);

  // cross-attn constants (diagonal mask -> one-hot softmax)
  for (int l=0; l<4; ++l){
    k_linear<<<dim3(4,48), 256, 0, stream>>>(content, 512, Wt_xa_v + (size_t)l*512*512, 512,
                                             xa_in_b + l*1536 + 1024, xtmp, 512, 512, 512);
    k_linear<<<dim3(4,48), 256, 0, stream>>>(xtmp, 512, Wt_xa_o + (size_t)l*512*512, 512,
                                             xa_out_b + l*512, xa_c + (size_t)l*384*512, 512, 512, 512);
  }

  // emb slot 0
  k_linear<<<dim3(4,1), 256, 0, stream>>>(init_st, 64, Wt_mm, 512, mm_b, catb, 1024, 512, 64);
  k_cat_tail<<<16, 256, 0, stream>>>(sel, catb);
  k_linear<<<dim3(4,1), 256, 0, stream>>>(catb, 1024, Wt_se, 512, se_b, embt, 512, 512, 1024);
  k_add_style<<<16, 256, 0, stream>>>(embt, style, emb);

  DP p;
  p.fl = fl; p.z = zacc; p.emb = emb; p.Vpriv = Vpriv;
  p.Wqkv = WqkvB; p.Wo = WoB; p.Wf1 = Wf1B; p.Wf2 = Wf2B;
  p.xa_c = xa_c; p.pe = pe;
  p.sa_in_b = sa_in_b; p.sa_out_b = sa_out_b; p.ff1_b = ff1_b; p.ff2_b = ff2_b;
  p.mmr_w = mmr_w; p.mmr_b = mmr_b; p.mm_w = mm_w; p.mm_b = mm_b;
  p.se_w = se_w; p.se_b = se_b; p.ln_g = ln_g; p.ln_b = ln_b;
  p.style = style; p.sel = sel; p.dec_out = dec_out;

  k_decode<<<dim3(128), dim3(256), 0, stream>>>(p);
}